// Round 13
// baseline (523.460 us; speedup 1.0000x reference)
//
#include <hip/hip_runtime.h>
#include <math.h>

typedef float f32x4 __attribute__((ext_vector_type(4)));

// R3/R8-exact scalar time loop (validated absmax=0.0): RN mul then RN add,
// no contraction, branchy soft reset via __fsub_rn, integer spike count.
// DO NOT rewrite into packed-vector/fma form: the R4/R6 vectorization
// produced absmax=2^-8 (near-threshold spike-timing flip).
template <int TT>
__device__ __forceinline__ void lif_elem(float ic, float tau, float thr, int T,
                                         float& m_out, int& s_out) {
    float m = 0.0f;
    int s = 0;
    if (TT > 0) {
#pragma unroll
        for (int t = 0; t < TT; ++t) {
            m = __fadd_rn(__fmul_rn(tau, m), ic);
            if (m >= thr) { m = __fsub_rn(m, thr); ++s; }
        }
    } else {
        for (int t = 0; t < T; ++t) {
            m = __fadd_rn(__fmul_rn(tau, m), ic);
            if (m >= thr) { m = __fsub_rn(m, thr); ++s; }
        }
    }
    m_out = m;
    s_out = s;
}

__global__ __launch_bounds__(256) void lif_fwd(
    const float* __restrict__ x,
    const float* __restrict__ thr_p,
    const float* __restrict__ tau_p,
    const int* __restrict__ ts_p,
    float* __restrict__ ssum,
    float* __restrict__ mem,
    float* __restrict__ partials,   // d_ws: one float per block, plain store (no init)
    int n4, int ntail)
{
    const float thr  = thr_p[0];
    const float traw = tau_p[0];
    const int   T    = ts_p[0];

    // tau = sigmoid(traw) = 1/(1+expf(-traw)); expf == __ocml_exp_f32, the same
    // libm XLA's exp lowers to on AMD -> bit-exact tau (validated absmax=0.0).
    const float e   = expf(-traw);
    const float tau = __fdiv_rn(1.0f, __fadd_rn(1.0f, e));
    const float tF  = (float)T;

    const f32x4* __restrict__ x4 = (const f32x4*)x;
    f32x4* __restrict__ ssum4 = (f32x4*)ssum;
    f32x4* __restrict__ mem4  = (f32x4*)mem;

    unsigned int cnt = 0;
    const int gtid   = blockIdx.x * blockDim.x + threadIdx.x;
    const int stride = gridDim.x * blockDim.x;

    // Tail elements (N not divisible by 4) — N=32*256*4096 here, so ntail==0.
    if (gtid < ntail) {
        const int idx = n4 * 4 + gtid;
        const float icv = __fdiv_rn(x[idx], tF);
        float m; int s;
        lif_elem<0>(icv, tau, thr, T, m, s);
        ssum[idx] = (float)s; mem[idx] = m; cnt += (unsigned int)s;
    }

#pragma unroll 4
    for (int i = gtid; i < n4; i += stride) {
        const f32x4 xv = x4[i];
        float ic[4];
#pragma unroll
        for (int j = 0; j < 4; ++j) ic[j] = __fdiv_rn(xv[j], tF);  // R3-exact

        float m[4];
        int   s[4];
        if (T == 8) {
#pragma unroll
            for (int j = 0; j < 4; ++j) lif_elem<8>(ic[j], tau, thr, T, m[j], s[j]);
        } else {
#pragma unroll
            for (int j = 0; j < 4; ++j) lif_elem<0>(ic[j], tau, thr, T, m[j], s[j]);
        }

        f32x4 sv = { (float)s[0], (float)s[1], (float)s[2], (float)s[3] };
        f32x4 mv = { m[0], m[1], m[2], m[3] };
        ssum4[i] = sv;
        mem4[i]  = mv;
        cnt += (unsigned int)(s[0] + s[1] + s[2] + s[3]);
    }

    // Exact integer block reduction: wave64 shuffle -> LDS -> one store/block.
    int c = (int)cnt;
    for (int off = 32; off > 0; off >>= 1)
        c += __shfl_down(c, off, 64);
    __shared__ int wred[4];             // 256 threads / 64 lanes
    const int lane = threadIdx.x & 63;
    const int wid  = threadIdx.x >> 6;
    if (lane == 0) wred[wid] = c;
    __syncthreads();
    if (threadIdx.x == 0)
        partials[blockIdx.x] = (float)(wred[0] + wred[1] + wred[2] + wred[3]);
}

__global__ __launch_bounds__(256) void lif_finalize(
    const float* __restrict__ partials, int nparts,
    const int* __restrict__ ts_p,
    float* __restrict__ reg_out, long long n)
{
    const int T = ts_p[0];
    double acc = 0.0;
    for (int i = threadIdx.x; i < nparts; i += 256)
        acc += (double)partials[i];     // partials are exact integers < 2^18
    for (int off = 32; off > 0; off >>= 1)
        acc += __shfl_down(acc, off, 64);
    __shared__ double dred[4];
    const int lane = threadIdx.x & 63;
    const int wid  = threadIdx.x >> 6;
    if (lane == 0) dred[wid] = acc;
    __syncthreads();
    if (threadIdx.x == 0) {
        const double total  = dred[0] + dred[1] + dred[2] + dred[3];
        const double mean_d = total / (double)n;
        const float  meanf  = (float)mean_d;
        const float  rate   = __fdiv_rn(meanf, (float)T);
        const float  d      = __fsub_rn(rate, 0.5f);
        reg_out[0] = __fmul_rn(0.01f, __fmul_rn(d, d));
    }
}

extern "C" void kernel_launch(void* const* d_in, const int* in_sizes, int n_in,
                              void* d_out, int out_size, void* d_ws, size_t ws_size,
                              hipStream_t stream) {
    const float* x   = (const float*)d_in[0];
    const float* thr = (const float*)d_in[1];
    const float* tau = (const float*)d_in[2];
    const int*   ts  = (const int*)d_in[3];
    const int N     = in_sizes[0];
    const int n4    = N / 4;
    const int ntail = N - n4 * 4;

    float* ssum = (float*)d_out;
    float* mem  = ssum + (size_t)N;
    float* reg  = ssum + (size_t)2 * N;
    float* partials = (float*)d_ws;     // grid floats of scratch; no init needed

    const int block = 256;
    int grid = (n4 + block - 1) / block;
    if (grid > 2048) grid = 2048;       // ~8 blocks/CU, grid-stride the rest
    if (grid < 1)    grid = 1;

    // R13 DIAGNOSTIC (second resubmit; infra failed before it ever ran):
    // lif_fwd is idempotent; launch 3x to measure its duration via dur_us:
    // L = (dur_R13 - 366.8)/2. Outputs bit-identical to a single launch.
    // Revert to 1x next round.
    hipLaunchKernelGGL(lif_fwd, dim3(grid), dim3(block), 0, stream,
                       x, thr, tau, ts, ssum, mem, partials, n4, ntail);
    hipLaunchKernelGGL(lif_fwd, dim3(grid), dim3(block), 0, stream,
                       x, thr, tau, ts, ssum, mem, partials, n4, ntail);
    hipLaunchKernelGGL(lif_fwd, dim3(grid), dim3(block), 0, stream,
                       x, thr, tau, ts, ssum, mem, partials, n4, ntail);
    hipLaunchKernelGGL(lif_finalize, dim3(1), dim3(block), 0, stream,
                       partials, grid, ts, reg, (long long)N);
}

// Round 14
// 364.925 us; speedup vs baseline: 1.4344x; 1.4344x over previous
//
#include <hip/hip_runtime.h>
#include <math.h>

typedef float f32x4 __attribute__((ext_vector_type(4)));

// R3/R8-exact scalar time loop (validated absmax=0.0): RN mul then RN add,
// no contraction, branchy soft reset via __fsub_rn, integer spike count.
// DO NOT rewrite into packed-vector/fma form: the R4/R6 vectorization
// produced absmax=2^-8 (near-threshold spike-timing flip).
//
// MEASURED (R13 3x-launch diagnostic): lif_fwd = 78.3us/launch = 5.1 TB/s
// implied (81% of 6.29 TB/s copy ceiling). dur_us = ~285us fixed harness
// restore/poison + 78us lif_fwd + ~3us finalize.
template <int TT>
__device__ __forceinline__ void lif_elem(float ic, float tau, float thr, int T,
                                         float& m_out, int& s_out) {
    float m = 0.0f;
    int s = 0;
    if (TT > 0) {
#pragma unroll
        for (int t = 0; t < TT; ++t) {
            m = __fadd_rn(__fmul_rn(tau, m), ic);
            if (m >= thr) { m = __fsub_rn(m, thr); ++s; }
        }
    } else {
        for (int t = 0; t < T; ++t) {
            m = __fadd_rn(__fmul_rn(tau, m), ic);
            if (m >= thr) { m = __fsub_rn(m, thr); ++s; }
        }
    }
    m_out = m;
    s_out = s;
}

__global__ __launch_bounds__(256) void lif_fwd(
    const float* __restrict__ x,
    const float* __restrict__ thr_p,
    const float* __restrict__ tau_p,
    const int* __restrict__ ts_p,
    float* __restrict__ ssum,
    float* __restrict__ mem,
    float* __restrict__ partials,   // d_ws: one float per block, plain store (no init)
    int n4, int ntail)
{
    const float thr  = thr_p[0];
    const float traw = tau_p[0];
    const int   T    = ts_p[0];

    // tau = sigmoid(traw) = 1/(1+expf(-traw)); expf == __ocml_exp_f32, the same
    // libm XLA's exp lowers to on AMD -> bit-exact tau (validated absmax=0.0).
    const float e   = expf(-traw);
    const float tau = __fdiv_rn(1.0f, __fadd_rn(1.0f, e));
    const float tF  = (float)T;

    const f32x4* __restrict__ x4 = (const f32x4*)x;
    f32x4* __restrict__ ssum4 = (f32x4*)ssum;
    f32x4* __restrict__ mem4  = (f32x4*)mem;

    unsigned int cnt = 0;
    const int gtid   = blockIdx.x * blockDim.x + threadIdx.x;
    const int stride = gridDim.x * blockDim.x;

    // Tail elements (N not divisible by 4) — N=32*256*4096 here, so ntail==0.
    if (gtid < ntail) {
        const int idx = n4 * 4 + gtid;
        const float icv = __fdiv_rn(x[idx], tF);
        float m; int s;
        lif_elem<0>(icv, tau, thr, T, m, s);
        ssum[idx] = (float)s; mem[idx] = m; cnt += (unsigned int)s;
    }

#pragma unroll 4
    for (int i = gtid; i < n4; i += stride) {
        // R14 single lever: non-temporal LOAD — x is read once; skipping
        // L2/L3 allocation leaves cache capacity to the 268MB write streams.
        const f32x4 xv = __builtin_nontemporal_load(&x4[i]);
        float ic[4];
#pragma unroll
        for (int j = 0; j < 4; ++j) ic[j] = __fdiv_rn(xv[j], tF);  // R3-exact

        float m[4];
        int   s[4];
        if (T == 8) {
#pragma unroll
            for (int j = 0; j < 4; ++j) lif_elem<8>(ic[j], tau, thr, T, m[j], s[j]);
        } else {
#pragma unroll
            for (int j = 0; j < 4; ++j) lif_elem<0>(ic[j], tau, thr, T, m[j], s[j]);
        }

        f32x4 sv = { (float)s[0], (float)s[1], (float)s[2], (float)s[3] };
        f32x4 mv = { m[0], m[1], m[2], m[3] };
        ssum4[i] = sv;
        mem4[i]  = mv;
        cnt += (unsigned int)(s[0] + s[1] + s[2] + s[3]);
    }

    // Exact integer block reduction: wave64 shuffle -> LDS -> one store/block.
    int c = (int)cnt;
    for (int off = 32; off > 0; off >>= 1)
        c += __shfl_down(c, off, 64);
    __shared__ int wred[4];             // 256 threads / 64 lanes
    const int lane = threadIdx.x & 63;
    const int wid  = threadIdx.x >> 6;
    if (lane == 0) wred[wid] = c;
    __syncthreads();
    if (threadIdx.x == 0)
        partials[blockIdx.x] = (float)(wred[0] + wred[1] + wred[2] + wred[3]);
}

__global__ __launch_bounds__(256) void lif_finalize(
    const float* __restrict__ partials, int nparts,
    const int* __restrict__ ts_p,
    float* __restrict__ reg_out, long long n)
{
    const int T = ts_p[0];
    double acc = 0.0;
    for (int i = threadIdx.x; i < nparts; i += 256)
        acc += (double)partials[i];     // partials are exact integers < 2^18
    for (int off = 32; off > 0; off >>= 1)
        acc += __shfl_down(acc, off, 64);
    __shared__ double dred[4];
    const int lane = threadIdx.x & 63;
    const int wid  = threadIdx.x >> 6;
    if (lane == 0) dred[wid] = acc;
    __syncthreads();
    if (threadIdx.x == 0) {
        const double total  = dred[0] + dred[1] + dred[2] + dred[3];
        const double mean_d = total / (double)n;
        const float  meanf  = (float)mean_d;
        const float  rate   = __fdiv_rn(meanf, (float)T);
        const float  d      = __fsub_rn(rate, 0.5f);
        reg_out[0] = __fmul_rn(0.01f, __fmul_rn(d, d));
    }
}

extern "C" void kernel_launch(void* const* d_in, const int* in_sizes, int n_in,
                              void* d_out, int out_size, void* d_ws, size_t ws_size,
                              hipStream_t stream) {
    const float* x   = (const float*)d_in[0];
    const float* thr = (const float*)d_in[1];
    const float* tau = (const float*)d_in[2];
    const int*   ts  = (const int*)d_in[3];
    const int N     = in_sizes[0];
    const int n4    = N / 4;
    const int ntail = N - n4 * 4;

    float* ssum = (float*)d_out;
    float* mem  = ssum + (size_t)N;
    float* reg  = ssum + (size_t)2 * N;
    float* partials = (float*)d_ws;     // grid floats of scratch; no init needed

    const int block = 256;
    int grid = (n4 + block - 1) / block;
    if (grid > 2048) grid = 2048;       // ~8 blocks/CU, grid-stride the rest
    if (grid < 1)    grid = 1;

    // Single launch restored (R11-R13 3x was a timing diagnostic only).
    hipLaunchKernelGGL(lif_fwd, dim3(grid), dim3(block), 0, stream,
                       x, thr, tau, ts, ssum, mem, partials, n4, ntail);
    hipLaunchKernelGGL(lif_finalize, dim3(1), dim3(block), 0, stream,
                       partials, grid, ts, reg, (long long)N);
}